// Round 7
// baseline (113337.427 us; speedup 1.0000x reference)
//
#include <hip/hip_runtime.h>

// RNNDetector: 2-layer LSTM (H=64), T=262144 sequential steps + 16-wide head.
// ROUND 17: R16 showed fdot2 and pk_fma run at the SAME rate (-4% only) ->
// VOP3P dot ops are ~4cyc/wave64; the 128-instr dot stream (~512cyc) IS the
// VALU floor. THIS ROUND: dots move to the MATRIX pipe.
//   gates[256] = W*h via v_mfma_f32_16x16x32_f16, A = h replicated in all 16
//   rows (lane loads ONE b128 of 8 h per K-slab; A-row map irrelevant since
//   rows equal; k-map errors cancel because A-load and B-pack share the map).
//   16 N-tiles x 2 K-slabs = 32 MFMA/step (~160cyc, off the VALU). D layout
//   (HW-verified m89): col=lane&15, row=4*(lane>>4)+reg -> lane l owns elem
//   e=l; its i/f/g/o sit on tiles {g,4+g,8+g,12+g} (g=l>>4) -> 12 cndmask
//   extract (reg0; rows replicated). VALU keeps only extract+activations.
// wave0: L0 recurrence (MFMA). wave1: xp1 = Wih1*h0+b via MFMA, written as
// stride-20 f32 [col][tile] (1 b128 write/step, conflict-free), + head
// (fdot2, unchanged). wave2: L1 recurrence (MFMA + 4 b32 xp reads).
// Weights packed in MFMA-B layout: lane l holds col c=l&15, k=8*(l>>4)+2q+{0,1}.

constexpr int T  = 262144;
constexpr int B  = 32;          // steps per superstep
constexpr int NB = T / B;       // 8192 blocks
constexpr int RS = 2 * B;       // 64 ring slots (2 blocks)
constexpr int K_SS = NB + 3;    // supersteps incl. pipeline drain

typedef _Float16 h2v  __attribute__((ext_vector_type(2)));
typedef _Float16 f16x8 __attribute__((ext_vector_type(8)));
typedef unsigned u4   __attribute__((ext_vector_type(4)));
typedef float    f4   __attribute__((ext_vector_type(4)));

__device__ __forceinline__ float rcp_f(float x) { return __builtin_amdgcn_rcpf(x); }

#define BARRIER() asm volatile("s_waitcnt lgkmcnt(0)\n\ts_barrier" ::: "memory")

// packed-f16 dot2 (head only): acc += w.lo*h.lo + w.hi*h.hi (f32 accumulate)
static __device__ __forceinline__ float fd(unsigned w, unsigned h, float acc) {
#if __has_builtin(__builtin_amdgcn_fdot2)
  return __builtin_amdgcn_fdot2(__builtin_bit_cast(h2v, w),
                                __builtin_bit_cast(h2v, h), acc, false);
#else
  h2v a = __builtin_bit_cast(h2v, w), b = __builtin_bit_cast(h2v, h);
  acc = fmaf((float)a.x, (float)b.x, acc);
  acc = fmaf((float)a.y, (float)b.y, acc);
  return acc;
#endif
}
#define DP4(acc, W, H) { acc = fd((W).x, (H).x, acc); acc = fd((W).y, (H).y, acc); \
                         acc = fd((W).z, (H).z, acc); acc = fd((W).w, (H).w, acc); }

// MFMA: D(16x16 f32) = A(16x32 f16) * B(32x16 f16) + C
__device__ __forceinline__ f4 mf(u4 a, u4 b, f4 c) {
  return __builtin_amdgcn_mfma_f32_16x16x32_f16(
      __builtin_bit_cast(f16x8, a), __builtin_bit_cast(f16x8, b), c, 0, 0, 0);
}

// runtime 4-way select by lane-group bits (3 cndmask)
__device__ __forceinline__ float sel4(float x0, float x1, float x2, float x3,
                                      bool b0, bool b1) {
  float lo = b0 ? x1 : x0;
  float hi = b0 ? x3 : x2;
  return b1 ? hi : lo;
}

// quad_perm DPP cross-lane (head reduce): xor1 = 0xB1, xor2 = 0x4E
#define DPPX1(x) __builtin_bit_cast(float, __builtin_amdgcn_mov_dpp(            \
                    __builtin_bit_cast(int, (x)), 0xB1, 0xF, 0xF, true))
#define DPPX2(x) __builtin_bit_cast(float, __builtin_amdgcn_mov_dpp(            \
                    __builtin_bit_cast(int, (x)), 0x4E, 0xF, 0xF, true))

// raw v_exp_f32 (2^x)
__device__ __forceinline__ float exp2_f(float x) {
  float r; asm("v_exp_f32 %0, %1" : "=v"(r) : "v"(x)); return r;
}
__device__ __forceinline__ float exp2n_g(float u) {
  return exp2_f(fminf(-u, 126.f));
}
__device__ __forceinline__ float sig_u(float u)  { return rcp_f(1.f + exp2n_g(u)); }
__device__ __forceinline__ float tanh_u(float u) {
  float e2 = exp2n_g(u);
  return (1.f - e2) * rcp_f(1.f + e2);
}
__device__ __forceinline__ float tanh_c(float c) {
  return tanh_u(c * 2.8853900817779268f);
}

constexpr float L2E  = 1.4426950408889634f;
constexpr float L2E2 = 2.8853900817779268f;

// f32 -> f16 RNE
__device__ unsigned f16rne(float f) {
  unsigned u = __float_as_uint(f);
  unsigned s = (u >> 16) & 0x8000u;
  int e = (int)((u >> 23) & 0xff) - 127;
  unsigned m = u & 0x7fffffu;
  if (e < -14) return s;
  unsigned h = s | (unsigned)((e + 15) << 10) | (m >> 13);
  unsigned rem = m & 0x1fffu;
  h += (rem > 0x1000u) || (rem == 0x1000u && (h & 1u));
  return h;
}

// ---- prepass: pack weights in MFMA-B layout, exp2-prescaled ----
// Regions (8192 dwords each): A=[0)Whh0(w0)  B=[8192)Whh1(w2)  C=[16384)Wih1(w1)
// Entry: lane l (c=l&15, g=l>>4), dword d: n=d>>3 (N-tile), s=(d>>2)&1 (K-slab),
//   q=d&3. Packs W[n*16+c][s*32+8g+2q .. +1] * scale, scale=2log2e iff n>>2==2.
//   (tile n covers ORIGINAL rows n*16+c: i:n<4, f:4-7, g:8-11, o:12-15.)
// Region E [24576,25088): head Wlin as before (unscaled).
__global__ void pack_w(const float* __restrict__ Whh0,
                       const float* __restrict__ Whh1,
                       const float* __restrict__ Wih1,
                       const float* __restrict__ Wlin,
                       unsigned* __restrict__ ws) {
  int i = blockIdx.x * 256 + threadIdx.x;
  if (i >= 25088) return;
  float v0, v1, sc = 1.f;
  if (i < 24576) {
    int w = i >> 13, rem = i & 8191, l = rem >> 7, d = rem & 127;
    int n = d >> 3, s = (d >> 2) & 1, q = d & 3;
    int c = l & 15, g = l >> 4;
    int row = n * 16 + c;
    int col = s * 32 + 8 * g + 2 * q;
    const float* src = (w == 0) ? Whh0 : (w == 1) ? Whh1 : Wih1;
    v0 = src[row * 64 + col]; v1 = src[row * 64 + col + 1];
    sc = ((n >> 2) == 2) ? L2E2 : L2E;
  } else {
    int j = i - 24576, l = j >> 3, d = j & 7;
    int m = l >> 2, kq = l & 3, k = kq * 16 + 2 * d;
    v0 = Wlin[m * 64 + k]; v1 = Wlin[m * 64 + k + 1];
  }
  ws[i] = f16rne(v0 * sc) | (f16rne(v1 * sc) << 16);
}

#define DECLW32(wp)                                                            \
  u4 W0=(wp)[0],  W1=(wp)[1],  W2=(wp)[2],  W3=(wp)[3],                        \
     W4=(wp)[4],  W5=(wp)[5],  W6=(wp)[6],  W7=(wp)[7],                        \
     W8=(wp)[8],  W9=(wp)[9],  W10=(wp)[10],W11=(wp)[11],                      \
     W12=(wp)[12],W13=(wp)[13],W14=(wp)[14],W15=(wp)[15],                      \
     W16=(wp)[16],W17=(wp)[17],W18=(wp)[18],W19=(wp)[19],                      \
     W20=(wp)[20],W21=(wp)[21],W22=(wp)[22],W23=(wp)[23],                      \
     W24=(wp)[24],W25=(wp)[25],W26=(wp)[26],W27=(wp)[27],                      \
     W28=(wp)[28],W29=(wp)[29],W30=(wp)[30],W31=(wp)[31]

#define PINW8(a,b,c,d,e,f,g,h)                                                 \
  asm volatile("" : "+v"(a), "+v"(b), "+v"(c), "+v"(d),                        \
                    "+v"(e), "+v"(f), "+v"(g), "+v"(h))
#define PINALL() { PINW8(W0,W1,W2,W3,W4,W5,W6,W7);                             \
                   PINW8(W8,W9,W10,W11,W12,W13,W14,W15);                       \
                   PINW8(W16,W17,W18,W19,W20,W21,W22,W23);                     \
                   PINW8(W24,W25,W26,W27,W28,W29,W30,W31); }

// 16-tile MFMA block: A0u/A1u = K-slab fragments (h), W0..W31 = B fragments.
#define MFMA16(A0u, A1u)                                                       \
  f4 a0  = mf(A0u, W0,  Z4); a0  = mf(A1u, W1,  a0);                           \
  f4 a1  = mf(A0u, W2,  Z4); a1  = mf(A1u, W3,  a1);                           \
  f4 a2  = mf(A0u, W4,  Z4); a2  = mf(A1u, W5,  a2);                           \
  f4 a3  = mf(A0u, W6,  Z4); a3  = mf(A1u, W7,  a3);                           \
  f4 a4  = mf(A0u, W8,  Z4); a4  = mf(A1u, W9,  a4);                           \
  f4 a5  = mf(A0u, W10, Z4); a5  = mf(A1u, W11, a5);                           \
  f4 a6  = mf(A0u, W12, Z4); a6  = mf(A1u, W13, a6);                           \
  f4 a7  = mf(A0u, W14, Z4); a7  = mf(A1u, W15, a7);                           \
  f4 a8  = mf(A0u, W16, Z4); a8  = mf(A1u, W17, a8);                           \
  f4 a9  = mf(A0u, W18, Z4); a9  = mf(A1u, W19, a9);                           \
  f4 a10 = mf(A0u, W20, Z4); a10 = mf(A1u, W21, a10);                          \
  f4 a11 = mf(A0u, W22, Z4); a11 = mf(A1u, W23, a11);                          \
  f4 a12 = mf(A0u, W24, Z4); a12 = mf(A1u, W25, a12);                          \
  f4 a13 = mf(A0u, W26, Z4); a13 = mf(A1u, W27, a13);                          \
  f4 a14 = mf(A0u, W28, Z4); a14 = mf(A1u, W29, a14);                          \
  f4 a15 = mf(A0u, W30, Z4); a15 = mf(A1u, W31, a15);

__global__ __launch_bounds__(192)
__attribute__((amdgpu_waves_per_eu(1, 1)))
void rnn_fused(
    const float* __restrict__ y,
    const float* __restrict__ Wih0, const float* __restrict__ bih0,
    const float* __restrict__ bhh0,
    const float* __restrict__ bih1, const float* __restrict__ bhh1,
    const float* __restrict__ blin,
    const unsigned* __restrict__ ws,
    float* __restrict__ out)
{
  const int tid = threadIdx.x;
  // rings: block j occupies slots [j*B .. j*B+B) & (RS-1); adjacent blocks in
  // disjoint halves -> cross-wave same-slot reuse >= 1 barrier apart.
  __shared__ __align__(16) unsigned h0r[RS * 32];    // h0 f16 by element, 8 KB
  __shared__ __align__(16) unsigned h1r[RS * 32];    // h1 f16 by element, 8 KB
  __shared__ __align__(16) float    xpf[RS * 320];   // xp f32 [col][tile] s20, 80 KB

  for (int j = tid; j < RS * 32; j += 192) { h0r[j] = 0u; h1r[j] = 0u; }
  __syncthreads();

  const f4 Z4 = {0.f, 0.f, 0.f, 0.f};

  if (tid < 64) {
    // ================= wave0: layer-0 recurrence via MFMA =================
    __builtin_amdgcn_s_setprio(1);
    const int e = tid, g = e >> 4;
    const bool b0 = (g & 1) != 0, b1 = (g & 2) != 0;
    const u4* wp = (const u4*)(ws + e * 128);          // Whh0, MFMA-B layout
    DECLW32(wp);
    float bbi = (bih0[e] + bhh0[e]) * L2E;
    float bbf = (bih0[64 + e] + bhh0[64 + e]) * L2E;
    float bbg = (bih0[128 + e] + bhh0[128 + e]) * L2E2;
    float bbo = (bih0[192 + e] + bhh0[192 + e]) * L2E;
    float wii = Wih0[e] * L2E, wif = Wih0[64 + e] * L2E;
    float wig = Wih0[128 + e] * L2E2, wio = Wih0[192 + e] * L2E;
    float c0 = 0.f;
    float ylv = y[e & (B - 1)];
    _Float16* h0h = (_Float16*)h0r;

    for (int k = 0; k < K_SS; ++k) {
      if (k < NB) {
        float yln = (k + 1 < NB) ? y[(k + 1) * B + (e & (B - 1))] : 0.f;
        const int base = k * B;
        #pragma unroll 1
        for (int i = 0; i < B; ++i) {
          const int s = base + i;
          PINALL();
          float ys = __builtin_bit_cast(float,
              __builtin_amdgcn_readlane(__builtin_bit_cast(int, ylv), i));
          const u4* ap = (const u4*)(h0r + ((s - 1) & (RS - 1)) * 32);
          u4 A0u = ap[g], A1u = ap[4 + g];             // h slabs (bcast per group)
          MFMA16(A0u, A1u)
          float ti = sel4(a0[0],  a1[0],  a2[0],  a3[0],  b0, b1);
          float tf = sel4(a4[0],  a5[0],  a6[0],  a7[0],  b0, b1);
          float tg = sel4(a8[0],  a9[0],  a10[0], a11[0], b0, b1);
          float to = sel4(a12[0], a13[0], a14[0], a15[0], b0, b1);
          float I = sig_u(ti + fmaf(ys, wii, bbi));
          float F = sig_u(tf + fmaf(ys, wif, bbf));
          float G = tanh_u(tg + fmaf(ys, wig, bbg));
          float O = sig_u(to + fmaf(ys, wio, bbo));
          c0 = fmaf(F, c0, I * G);
          float h = O * tanh_c(c0);
          h0h[(s & (RS - 1)) * 64 + e] = (_Float16)h;  // ds_write_b16
        }
        ylv = yln;
      }
      BARRIER();
    }
  } else if (tid < 128) {
    // ====== wave1: xp1 = Wih1*h0+b via MFMA (block k-1) + head (k-3) ======
    const int e = tid - 64, g = e >> 4, c = e & 15;
    const bool b0 = (g & 1) != 0, b1 = (g & 2) != 0;
    const u4* wp = (const u4*)(ws + 16384 + e * 128);  // Wih1, MFMA-B layout
    DECLW32(wp);
    const u4* hwp = (const u4*)(ws + 24576 + e * 8);
    u4 HW0 = hwp[0], HW1 = hwp[1];
    // per-lane biases for the 4 tiles this lane writes (tiles 4g..4g+3, col c)
    float bbx, bby, bbz, bbw;
    {
      int R0 = (4 * g + 0) * 16 + c, R1 = (4 * g + 1) * 16 + c;
      int R2 = (4 * g + 2) * 16 + c, R3 = (4 * g + 3) * 16 + c;
      float s0 = (((4 * g + 0) >> 2) == 2) ? L2E2 : L2E;
      float s1 = (((4 * g + 1) >> 2) == 2) ? L2E2 : L2E;
      float s2 = (((4 * g + 2) >> 2) == 2) ? L2E2 : L2E;
      float s3 = (((4 * g + 3) >> 2) == 2) ? L2E2 : L2E;
      bbx = (bih1[R0] + bhh1[R0]) * s0; bby = (bih1[R1] + bhh1[R1]) * s1;
      bbz = (bih1[R2] + bhh1[R2]) * s2; bbw = (bih1[R3] + bhh1[R3]) * s3;
    }
    const int m = e >> 2, kq = e & 3;
    float bl = (kq == 0) ? blin[m] : 0.f;

    for (int k = 0; k < K_SS; ++k) {
      if (k >= 1 && k <= NB) {                         // xp1 for block k-1
        const int base = (k - 1) * B;
        #pragma unroll 1
        for (int i = 0; i < B; ++i) {
          const int t = base + i;
          const int slot = t & (RS - 1);
          PINALL();
          const u4* ap = (const u4*)(h0r + slot * 32);
          u4 A0u = ap[g], A1u = ap[4 + g];
          MFMA16(A0u, A1u)
          // lane writes tiles 4g+j at [c][4g+j]; tile (4g+j) = sel by g
          float vx = sel4(a0[0], a4[0], a8[0],  a12[0], b0, b1) + bbx;
          float vy = sel4(a1[0], a5[0], a9[0],  a13[0], b0, b1) + bby;
          float vz = sel4(a2[0], a6[0], a10[0], a14[0], b0, b1) + bbz;
          float vw = sel4(a3[0], a7[0], a11[0], a15[0], b0, b1) + bbw;
          f4 v = {vx, vy, vz, vw};
          *(f4*)(xpf + slot * 320 + c * 20 + 4 * g) = v;   // one ds_write_b128
        }
      }
      if (k >= 3) {                                    // head for block k-3
        const int base = (k - 3) * B;
        #pragma unroll 1
        for (int i = 0; i < B; ++i) {
          const int t = base + i;
          const int slot = t & (RS - 1);
          const u4* h1p = (const u4*)(h1r + slot * 32 + kq * 8);
          u4 X0 = h1p[0], X1 = h1p[1];
          float r2 = 0.f;
          DP4(r2, HW0, X0) DP4(r2, HW1, X1)
          r2 += DPPX1(r2);
          r2 += DPPX2(r2);                             // sum over kq (quad)
          if (kq == 0) out[t * 16 + m] = r2 + bl;
        }
      }
      BARRIER();
    }
  } else {
    // ============ wave2: layer-1 recurrence via MFMA (block k-2) ============
    __builtin_amdgcn_s_setprio(1);
    const int e = tid - 128, g = e >> 4, c = e & 15;
    const bool b0 = (g & 1) != 0, b1 = (g & 2) != 0;
    const u4* wp = (const u4*)(ws + 8192 + e * 128);   // Whh1, MFMA-B layout
    DECLW32(wp);
    float c1 = 0.f;
    _Float16* h1h = (_Float16*)h1r;

    for (int k = 0; k < K_SS; ++k) {
      if (k >= 2 && k <= NB + 1) {
        const int base = (k - 2) * B;
        #pragma unroll 1
        for (int i = 0; i < B; ++i) {
          const int t = base + i;
          const int slot = t & (RS - 1);
          PINALL();
          const float* xb = xpf + slot * 320 + c * 20;
          float xi = xb[g], xf = xb[4 + g], xg2 = xb[8 + g], xo = xb[12 + g];
          const u4* ap = (const u4*)(h1r + ((t - 1) & (RS - 1)) * 32);
          u4 A0u = ap[g], A1u = ap[4 + g];
          MFMA16(A0u, A1u)
          float ti = sel4(a0[0],  a1[0],  a2[0],  a3[0],  b0, b1);
          float tf = sel4(a4[0],  a5[0],  a6[0],  a7[0],  b0, b1);
          float tg = sel4(a8[0],  a9[0],  a10[0], a11[0], b0, b1);
          float to = sel4(a12[0], a13[0], a14[0], a15[0], b0, b1);
          float I = sig_u(ti + xi);
          float F = sig_u(tf + xf);
          float G = tanh_u(tg + xg2);
          float O = sig_u(to + xo);
          c1 = fmaf(F, c1, I * G);
          float h = O * tanh_c(c1);
          h1h[slot * 64 + e] = (_Float16)h;            // ds_write_b16
        }
      }
      BARRIER();
    }
  }
}

extern "C" void kernel_launch(void* const* d_in, const int* in_sizes, int n_in,
                              void* d_out, int out_size, void* d_ws, size_t ws_size,
                              hipStream_t stream) {
  const float* y    = (const float*)d_in[0];
  const float* Wih0 = (const float*)d_in[1];
  const float* Whh0 = (const float*)d_in[2];
  const float* bih0 = (const float*)d_in[3];
  const float* bhh0 = (const float*)d_in[4];
  const float* Wih1 = (const float*)d_in[5];
  const float* Whh1 = (const float*)d_in[6];
  const float* bih1 = (const float*)d_in[7];
  const float* bhh1 = (const float*)d_in[8];
  const float* Wlin = (const float*)d_in[9];
  const float* blin = (const float*)d_in[10];
  unsigned* ws = (unsigned*)d_ws;                // 25088 dwords ~= 100 KB

  pack_w<<<dim3(98), dim3(256), 0, stream>>>(Whh0, Whh1, Wih1, Wlin, ws);
  rnn_fused<<<dim3(1), dim3(192), 0, stream>>>(
      y, Wih0, bih0, bhh0, bih1, bhh1, blin, ws, (float*)d_out);
}

// Round 8
// 109159.204 us; speedup vs baseline: 1.0383x; 1.0383x over previous
//
#include <hip/hip_runtime.h>

// RNNDetector: 2-layer LSTM (H=64), T=262144 sequential steps + 16-wide head.
// ROUND 18: R17 (MFMA) matched R16/R13 at ~1040cyc/step -- step time is
// INVARIANT across fdot2/pk_fma/MFMA engines. Recurrence issue is exonerated.
// Two hypotheses left: (H1) pipeline paced by helper wave1 (32 MFMA + xp
// write + whole head per step; every barrier waits on it); (H2) paced by the
// serial dependency loop itself (~1000cyc true latency). THIS ROUND probes
// and (if H1) fixes H1 in one move: use the CU's idle 4th SIMD.
//   wave0: L0 recurrence (unchanged)        wave2: L1 recurrence (unchanged)
//   wave1: xp1 via MFMA, steps 0-15         wave3: xp1 steps 16-31 + head
// If dur drops -> H1 (helper-paced). If flat -> H2; R19 shortens the serial
// chain (register-resident h, no sel4 extract).

constexpr int T  = 262144;
constexpr int B  = 32;          // steps per superstep
constexpr int NB = T / B;       // 8192 blocks
constexpr int RS = 2 * B;       // 64 ring slots (2 blocks)
constexpr int K_SS = NB + 3;    // supersteps incl. pipeline drain

typedef _Float16 h2v  __attribute__((ext_vector_type(2)));
typedef _Float16 f16x8 __attribute__((ext_vector_type(8)));
typedef unsigned u4   __attribute__((ext_vector_type(4)));
typedef float    f4   __attribute__((ext_vector_type(4)));

__device__ __forceinline__ float rcp_f(float x) { return __builtin_amdgcn_rcpf(x); }

#define BARRIER() asm volatile("s_waitcnt lgkmcnt(0)\n\ts_barrier" ::: "memory")

// packed-f16 dot2 (head only): acc += w.lo*h.lo + w.hi*h.hi (f32 accumulate)
static __device__ __forceinline__ float fd(unsigned w, unsigned h, float acc) {
#if __has_builtin(__builtin_amdgcn_fdot2)
  return __builtin_amdgcn_fdot2(__builtin_bit_cast(h2v, w),
                                __builtin_bit_cast(h2v, h), acc, false);
#else
  h2v a = __builtin_bit_cast(h2v, w), b = __builtin_bit_cast(h2v, h);
  acc = fmaf((float)a.x, (float)b.x, acc);
  acc = fmaf((float)a.y, (float)b.y, acc);
  return acc;
#endif
}
#define DP4(acc, W, H) { acc = fd((W).x, (H).x, acc); acc = fd((W).y, (H).y, acc); \
                         acc = fd((W).z, (H).z, acc); acc = fd((W).w, (H).w, acc); }

// MFMA: D(16x16 f32) = A(16x32 f16) * B(32x16 f16) + C
__device__ __forceinline__ f4 mf(u4 a, u4 b, f4 c) {
  return __builtin_amdgcn_mfma_f32_16x16x32_f16(
      __builtin_bit_cast(f16x8, a), __builtin_bit_cast(f16x8, b), c, 0, 0, 0);
}

// runtime 4-way select by lane-group bits (3 cndmask)
__device__ __forceinline__ float sel4(float x0, float x1, float x2, float x3,
                                      bool b0, bool b1) {
  float lo = b0 ? x1 : x0;
  float hi = b0 ? x3 : x2;
  return b1 ? hi : lo;
}

// quad_perm DPP cross-lane (head reduce): xor1 = 0xB1, xor2 = 0x4E
#define DPPX1(x) __builtin_bit_cast(float, __builtin_amdgcn_mov_dpp(            \
                    __builtin_bit_cast(int, (x)), 0xB1, 0xF, 0xF, true))
#define DPPX2(x) __builtin_bit_cast(float, __builtin_amdgcn_mov_dpp(            \
                    __builtin_bit_cast(int, (x)), 0x4E, 0xF, 0xF, true))

// raw v_exp_f32 (2^x)
__device__ __forceinline__ float exp2_f(float x) {
  float r; asm("v_exp_f32 %0, %1" : "=v"(r) : "v"(x)); return r;
}
__device__ __forceinline__ float exp2n_g(float u) {
  return exp2_f(fminf(-u, 126.f));
}
__device__ __forceinline__ float sig_u(float u)  { return rcp_f(1.f + exp2n_g(u)); }
__device__ __forceinline__ float tanh_u(float u) {
  float e2 = exp2n_g(u);
  return (1.f - e2) * rcp_f(1.f + e2);
}
__device__ __forceinline__ float tanh_c(float c) {
  return tanh_u(c * 2.8853900817779268f);
}

constexpr float L2E  = 1.4426950408889634f;
constexpr float L2E2 = 2.8853900817779268f;

// f32 -> f16 RNE
__device__ unsigned f16rne(float f) {
  unsigned u = __float_as_uint(f);
  unsigned s = (u >> 16) & 0x8000u;
  int e = (int)((u >> 23) & 0xff) - 127;
  unsigned m = u & 0x7fffffu;
  if (e < -14) return s;
  unsigned h = s | (unsigned)((e + 15) << 10) | (m >> 13);
  unsigned rem = m & 0x1fffu;
  h += (rem > 0x1000u) || (rem == 0x1000u && (h & 1u));
  return h;
}

// ---- prepass: pack weights in MFMA-B layout, exp2-prescaled ----
// Regions (8192 dwords each): A=[0)Whh0(w0)  B=[8192)Whh1(w2)  C=[16384)Wih1(w1/w3)
// Entry: lane l (c=l&15, g=l>>4), dword d: n=d>>3 (N-tile), s=(d>>2)&1 (K-slab),
//   q=d&3. Packs W[n*16+c][s*32+8g+2q .. +1] * scale, scale=2log2e iff n>>2==2.
// Region E [24576,25088): head Wlin as before (unscaled).
__global__ void pack_w(const float* __restrict__ Whh0,
                       const float* __restrict__ Whh1,
                       const float* __restrict__ Wih1,
                       const float* __restrict__ Wlin,
                       unsigned* __restrict__ ws) {
  int i = blockIdx.x * 256 + threadIdx.x;
  if (i >= 25088) return;
  float v0, v1, sc = 1.f;
  if (i < 24576) {
    int w = i >> 13, rem = i & 8191, l = rem >> 7, d = rem & 127;
    int n = d >> 3, s = (d >> 2) & 1, q = d & 3;
    int c = l & 15, g = l >> 4;
    int row = n * 16 + c;
    int col = s * 32 + 8 * g + 2 * q;
    const float* src = (w == 0) ? Whh0 : (w == 1) ? Whh1 : Wih1;
    v0 = src[row * 64 + col]; v1 = src[row * 64 + col + 1];
    sc = ((n >> 2) == 2) ? L2E2 : L2E;
  } else {
    int j = i - 24576, l = j >> 3, d = j & 7;
    int m = l >> 2, kq = l & 3, k = kq * 16 + 2 * d;
    v0 = Wlin[m * 64 + k]; v1 = Wlin[m * 64 + k + 1];
  }
  ws[i] = f16rne(v0 * sc) | (f16rne(v1 * sc) << 16);
}

#define DECLW32(wp)                                                            \
  u4 W0=(wp)[0],  W1=(wp)[1],  W2=(wp)[2],  W3=(wp)[3],                        \
     W4=(wp)[4],  W5=(wp)[5],  W6=(wp)[6],  W7=(wp)[7],                        \
     W8=(wp)[8],  W9=(wp)[9],  W10=(wp)[10],W11=(wp)[11],                      \
     W12=(wp)[12],W13=(wp)[13],W14=(wp)[14],W15=(wp)[15],                      \
     W16=(wp)[16],W17=(wp)[17],W18=(wp)[18],W19=(wp)[19],                      \
     W20=(wp)[20],W21=(wp)[21],W22=(wp)[22],W23=(wp)[23],                      \
     W24=(wp)[24],W25=(wp)[25],W26=(wp)[26],W27=(wp)[27],                      \
     W28=(wp)[28],W29=(wp)[29],W30=(wp)[30],W31=(wp)[31]

#define PINW8(a,b,c,d,e,f,g,h)                                                 \
  asm volatile("" : "+v"(a), "+v"(b), "+v"(c), "+v"(d),                        \
                    "+v"(e), "+v"(f), "+v"(g), "+v"(h))
#define PINALL() { PINW8(W0,W1,W2,W3,W4,W5,W6,W7);                             \
                   PINW8(W8,W9,W10,W11,W12,W13,W14,W15);                       \
                   PINW8(W16,W17,W18,W19,W20,W21,W22,W23);                     \
                   PINW8(W24,W25,W26,W27,W28,W29,W30,W31); }

// 16-tile MFMA block: A0u/A1u = K-slab fragments (h), W0..W31 = B fragments.
#define MFMA16(A0u, A1u)                                                       \
  f4 a0  = mf(A0u, W0,  Z4); a0  = mf(A1u, W1,  a0);                           \
  f4 a1  = mf(A0u, W2,  Z4); a1  = mf(A1u, W3,  a1);                           \
  f4 a2  = mf(A0u, W4,  Z4); a2  = mf(A1u, W5,  a2);                           \
  f4 a3  = mf(A0u, W6,  Z4); a3  = mf(A1u, W7,  a3);                           \
  f4 a4  = mf(A0u, W8,  Z4); a4  = mf(A1u, W9,  a4);                           \
  f4 a5  = mf(A0u, W10, Z4); a5  = mf(A1u, W11, a5);                           \
  f4 a6  = mf(A0u, W12, Z4); a6  = mf(A1u, W13, a6);                           \
  f4 a7  = mf(A0u, W14, Z4); a7  = mf(A1u, W15, a7);                           \
  f4 a8  = mf(A0u, W16, Z4); a8  = mf(A1u, W17, a8);                           \
  f4 a9  = mf(A0u, W18, Z4); a9  = mf(A1u, W19, a9);                           \
  f4 a10 = mf(A0u, W20, Z4); a10 = mf(A1u, W21, a10);                          \
  f4 a11 = mf(A0u, W22, Z4); a11 = mf(A1u, W23, a11);                          \
  f4 a12 = mf(A0u, W24, Z4); a12 = mf(A1u, W25, a12);                          \
  f4 a13 = mf(A0u, W26, Z4); a13 = mf(A1u, W27, a13);                          \
  f4 a14 = mf(A0u, W28, Z4); a14 = mf(A1u, W29, a14);                          \
  f4 a15 = mf(A0u, W30, Z4); a15 = mf(A1u, W31, a15);

__global__ __launch_bounds__(256)
__attribute__((amdgpu_waves_per_eu(1, 1)))
void rnn_fused(
    const float* __restrict__ y,
    const float* __restrict__ Wih0, const float* __restrict__ bih0,
    const float* __restrict__ bhh0,
    const float* __restrict__ bih1, const float* __restrict__ bhh1,
    const float* __restrict__ blin,
    const unsigned* __restrict__ ws,
    float* __restrict__ out)
{
  const int tid = threadIdx.x;
  const int w = tid >> 6;
  // rings: block j occupies slots [j*B .. j*B+B) & (RS-1); adjacent blocks in
  // disjoint halves -> cross-wave same-slot reuse >= 1 barrier apart.
  __shared__ __align__(16) unsigned h0r[RS * 32];    // h0 f16 by element, 8 KB
  __shared__ __align__(16) unsigned h1r[RS * 32];    // h1 f16 by element, 8 KB
  __shared__ __align__(16) float    xpf[RS * 320];   // xp f32 [col][tile] s20, 80 KB

  for (int j = tid; j < RS * 32; j += 256) { h0r[j] = 0u; h1r[j] = 0u; }
  __syncthreads();

  const f4 Z4 = {0.f, 0.f, 0.f, 0.f};

  if (w == 0) {
    // ================= wave0: layer-0 recurrence via MFMA =================
    __builtin_amdgcn_s_setprio(1);
    const int e = tid, g = e >> 4;
    const bool b0 = (g & 1) != 0, b1 = (g & 2) != 0;
    const u4* wp = (const u4*)(ws + e * 128);          // Whh0, MFMA-B layout
    DECLW32(wp);
    float bbi = (bih0[e] + bhh0[e]) * L2E;
    float bbf = (bih0[64 + e] + bhh0[64 + e]) * L2E;
    float bbg = (bih0[128 + e] + bhh0[128 + e]) * L2E2;
    float bbo = (bih0[192 + e] + bhh0[192 + e]) * L2E;
    float wii = Wih0[e] * L2E, wif = Wih0[64 + e] * L2E;
    float wig = Wih0[128 + e] * L2E2, wio = Wih0[192 + e] * L2E;
    float c0 = 0.f;
    float ylv = y[e & (B - 1)];
    _Float16* h0h = (_Float16*)h0r;

    for (int k = 0; k < K_SS; ++k) {
      if (k < NB) {
        float yln = (k + 1 < NB) ? y[(k + 1) * B + (e & (B - 1))] : 0.f;
        const int base = k * B;
        #pragma unroll 1
        for (int i = 0; i < B; ++i) {
          const int s = base + i;
          PINALL();
          float ys = __builtin_bit_cast(float,
              __builtin_amdgcn_readlane(__builtin_bit_cast(int, ylv), i));
          const u4* ap = (const u4*)(h0r + ((s - 1) & (RS - 1)) * 32);
          u4 A0u = ap[g], A1u = ap[4 + g];             // h slabs (bcast per group)
          MFMA16(A0u, A1u)
          float ti = sel4(a0[0],  a1[0],  a2[0],  a3[0],  b0, b1);
          float tf = sel4(a4[0],  a5[0],  a6[0],  a7[0],  b0, b1);
          float tg = sel4(a8[0],  a9[0],  a10[0], a11[0], b0, b1);
          float to = sel4(a12[0], a13[0], a14[0], a15[0], b0, b1);
          float I = sig_u(ti + fmaf(ys, wii, bbi));
          float F = sig_u(tf + fmaf(ys, wif, bbf));
          float G = tanh_u(tg + fmaf(ys, wig, bbg));
          float O = sig_u(to + fmaf(ys, wio, bbo));
          c0 = fmaf(F, c0, I * G);
          float h = O * tanh_c(c0);
          h0h[(s & (RS - 1)) * 64 + e] = (_Float16)h;  // ds_write_b16
        }
        ylv = yln;
      }
      BARRIER();
    }
  } else if (w == 1 || w == 3) {
    // == wave1/wave3: xp1 = Wih1*h0+b via MFMA (block k-1, split 16 steps) ==
    //    wave3 additionally owns the head (block k-3, all 32 steps).
    const int e = tid & 63, g = e >> 4, c = e & 15;
    const bool b0 = (g & 1) != 0, b1 = (g & 2) != 0;
    const int ilo = (w == 1) ? 0 : 16;
    const u4* wp = (const u4*)(ws + 16384 + e * 128);  // Wih1, MFMA-B layout
    DECLW32(wp);
    const u4* hwp = (const u4*)(ws + 24576 + e * 8);
    u4 HW0 = hwp[0], HW1 = hwp[1];
    // per-lane biases for the 4 tiles this lane writes (tiles 4g..4g+3, col c)
    float bbx, bby, bbz, bbw;
    {
      int R0 = (4 * g + 0) * 16 + c, R1 = (4 * g + 1) * 16 + c;
      int R2 = (4 * g + 2) * 16 + c, R3 = (4 * g + 3) * 16 + c;
      float s0 = (((4 * g + 0) >> 2) == 2) ? L2E2 : L2E;
      float s1 = (((4 * g + 1) >> 2) == 2) ? L2E2 : L2E;
      float s2 = (((4 * g + 2) >> 2) == 2) ? L2E2 : L2E;
      float s3 = (((4 * g + 3) >> 2) == 2) ? L2E2 : L2E;
      bbx = (bih1[R0] + bhh1[R0]) * s0; bby = (bih1[R1] + bhh1[R1]) * s1;
      bbz = (bih1[R2] + bhh1[R2]) * s2; bbw = (bih1[R3] + bhh1[R3]) * s3;
    }
    const int m = e >> 2, kq = e & 3;
    float bl = (kq == 0) ? blin[m] : 0.f;

    for (int k = 0; k < K_SS; ++k) {
      if (k >= 1 && k <= NB) {                         // xp1 for block k-1
        const int base = (k - 1) * B;
        #pragma unroll 1
        for (int i = ilo; i < ilo + 16; ++i) {
          const int t = base + i;
          const int slot = t & (RS - 1);
          PINALL();
          const u4* ap = (const u4*)(h0r + slot * 32);
          u4 A0u = ap[g], A1u = ap[4 + g];
          MFMA16(A0u, A1u)
          // lane writes tiles 4g+j at [c][4g+j]; tile (4g+j) = sel by g
          float vx = sel4(a0[0], a4[0], a8[0],  a12[0], b0, b1) + bbx;
          float vy = sel4(a1[0], a5[0], a9[0],  a13[0], b0, b1) + bby;
          float vz = sel4(a2[0], a6[0], a10[0], a14[0], b0, b1) + bbz;
          float vw = sel4(a3[0], a7[0], a11[0], a15[0], b0, b1) + bbw;
          f4 v = {vx, vy, vz, vw};
          *(f4*)(xpf + slot * 320 + c * 20 + 4 * g) = v;   // one ds_write_b128
        }
      }
      if (w == 3 && k >= 3) {                          // head for block k-3
        const int base = (k - 3) * B;
        #pragma unroll 1
        for (int i = 0; i < B; ++i) {
          const int t = base + i;
          const int slot = t & (RS - 1);
          const u4* h1p = (const u4*)(h1r + slot * 32 + kq * 8);
          u4 X0 = h1p[0], X1 = h1p[1];
          float r2 = 0.f;
          DP4(r2, HW0, X0) DP4(r2, HW1, X1)
          r2 += DPPX1(r2);
          r2 += DPPX2(r2);                             // sum over kq (quad)
          if (kq == 0) out[t * 16 + m] = r2 + bl;
        }
      }
      BARRIER();
    }
  } else {
    // ============ wave2: layer-1 recurrence via MFMA (block k-2) ============
    __builtin_amdgcn_s_setprio(1);
    const int e = tid - 128, g = e >> 4, c = e & 15;
    const bool b0 = (g & 1) != 0, b1 = (g & 2) != 0;
    const u4* wp = (const u4*)(ws + 8192 + e * 128);   // Whh1, MFMA-B layout
    DECLW32(wp);
    float c1 = 0.f;
    _Float16* h1h = (_Float16*)h1r;

    for (int k = 0; k < K_SS; ++k) {
      if (k >= 2 && k <= NB + 1) {
        const int base = (k - 2) * B;
        #pragma unroll 1
        for (int i = 0; i < B; ++i) {
          const int t = base + i;
          const int slot = t & (RS - 1);
          PINALL();
          const float* xb = xpf + slot * 320 + c * 20;
          float xi = xb[g], xf = xb[4 + g], xg2 = xb[8 + g], xo = xb[12 + g];
          const u4* ap = (const u4*)(h1r + ((t - 1) & (RS - 1)) * 32);
          u4 A0u = ap[g], A1u = ap[4 + g];
          MFMA16(A0u, A1u)
          float ti = sel4(a0[0],  a1[0],  a2[0],  a3[0],  b0, b1);
          float tf = sel4(a4[0],  a5[0],  a6[0],  a7[0],  b0, b1);
          float tg = sel4(a8[0],  a9[0],  a10[0], a11[0], b0, b1);
          float to = sel4(a12[0], a13[0], a14[0], a15[0], b0, b1);
          float I = sig_u(ti + xi);
          float F = sig_u(tf + xf);
          float G = tanh_u(tg + xg2);
          float O = sig_u(to + xo);
          c1 = fmaf(F, c1, I * G);
          float h = O * tanh_c(c1);
          h1h[slot * 64 + e] = (_Float16)h;            // ds_write_b16
        }
      }
      BARRIER();
    }
  }
}

extern "C" void kernel_launch(void* const* d_in, const int* in_sizes, int n_in,
                              void* d_out, int out_size, void* d_ws, size_t ws_size,
                              hipStream_t stream) {
  const float* y    = (const float*)d_in[0];
  const float* Wih0 = (const float*)d_in[1];
  const float* Whh0 = (const float*)d_in[2];
  const float* bih0 = (const float*)d_in[3];
  const float* bhh0 = (const float*)d_in[4];
  const float* Wih1 = (const float*)d_in[5];
  const float* Whh1 = (const float*)d_in[6];
  const float* bih1 = (const float*)d_in[7];
  const float* bhh1 = (const float*)d_in[8];
  const float* Wlin = (const float*)d_in[9];
  const float* blin = (const float*)d_in[10];
  unsigned* ws = (unsigned*)d_ws;                // 25088 dwords ~= 100 KB

  pack_w<<<dim3(98), dim3(256), 0, stream>>>(Whh0, Whh1, Wih1, Wlin, ws);
  rnn_fused<<<dim3(1), dim3(256), 0, stream>>>(
      y, Wih0, bih0, bhh0, bih1, bhh1, blin, ws, (float*)d_out);
}

// Round 9
// 107133.582 us; speedup vs baseline: 1.0579x; 1.0189x over previous
//
#include <hip/hip_runtime.h>

// RNNDetector: 2-layer LSTM (H=64), T=262144 sequential steps + 16-wide head.
// ROUND 19: R18 killed H1 (helper-paced): 4th SIMD + split xp -> no change.
// Step time ~1000"cyc" is now invariant to: dot engine (fdot2/pk_fma/MFMA),
// LDS op count (4x), VALU issue (2x), helper load. A chain built from these
// components can't be invariant to all of them -> external pacer. Prime
// suspect remains SCLK: R15's spinners measured VALUBusy=1.3% (they barely
// issued: s_sleep + per-iter global atomic poll), so that refutation was
// invalid. Model chain ~430cyc; measured 416ns = the model at ~1.0GHz.
// THIS ROUND: same main kernel (R18 bit-identical) + 255 spinner WGs of
// dense ILP-8 FMA (2048 FMA per flag poll, NO sleep). The probe self-checks:
// VALUBusy must read >40% or the spinners didn't run. dur drops -> clock was
// parked (keep spinners). dur flat with VALUBusy high -> clock exonerated,
// R20 restructures the serial chain (MFMA interleave + bpermute h-exchange).

constexpr int T  = 262144;
constexpr int B  = 32;          // steps per superstep
constexpr int NB = T / B;       // 8192 blocks
constexpr int RS = 2 * B;       // 64 ring slots (2 blocks)
constexpr int K_SS = NB + 3;    // supersteps incl. pipeline drain
constexpr int FLAG = 25088;     // ws dword: done-flag for spinner WGs

typedef _Float16 h2v  __attribute__((ext_vector_type(2)));
typedef _Float16 f16x8 __attribute__((ext_vector_type(8)));
typedef unsigned u4   __attribute__((ext_vector_type(4)));
typedef float    f4   __attribute__((ext_vector_type(4)));

__device__ __forceinline__ float rcp_f(float x) { return __builtin_amdgcn_rcpf(x); }

#define BARRIER() asm volatile("s_waitcnt lgkmcnt(0)\n\ts_barrier" ::: "memory")

// packed-f16 dot2 (head only): acc += w.lo*h.lo + w.hi*h.hi (f32 accumulate)
static __device__ __forceinline__ float fd(unsigned w, unsigned h, float acc) {
#if __has_builtin(__builtin_amdgcn_fdot2)
  return __builtin_amdgcn_fdot2(__builtin_bit_cast(h2v, w),
                                __builtin_bit_cast(h2v, h), acc, false);
#else
  h2v a = __builtin_bit_cast(h2v, w), b = __builtin_bit_cast(h2v, h);
  acc = fmaf((float)a.x, (float)b.x, acc);
  acc = fmaf((float)a.y, (float)b.y, acc);
  return acc;
#endif
}
#define DP4(acc, W, H) { acc = fd((W).x, (H).x, acc); acc = fd((W).y, (H).y, acc); \
                         acc = fd((W).z, (H).z, acc); acc = fd((W).w, (H).w, acc); }

// MFMA: D(16x16 f32) = A(16x32 f16) * B(32x16 f16) + C
__device__ __forceinline__ f4 mf(u4 a, u4 b, f4 c) {
  return __builtin_amdgcn_mfma_f32_16x16x32_f16(
      __builtin_bit_cast(f16x8, a), __builtin_bit_cast(f16x8, b), c, 0, 0, 0);
}

// runtime 4-way select by lane-group bits (3 cndmask)
__device__ __forceinline__ float sel4(float x0, float x1, float x2, float x3,
                                      bool b0, bool b1) {
  float lo = b0 ? x1 : x0;
  float hi = b0 ? x3 : x2;
  return b1 ? hi : lo;
}

// quad_perm DPP cross-lane (head reduce): xor1 = 0xB1, xor2 = 0x4E
#define DPPX1(x) __builtin_bit_cast(float, __builtin_amdgcn_mov_dpp(            \
                    __builtin_bit_cast(int, (x)), 0xB1, 0xF, 0xF, true))
#define DPPX2(x) __builtin_bit_cast(float, __builtin_amdgcn_mov_dpp(            \
                    __builtin_bit_cast(int, (x)), 0x4E, 0xF, 0xF, true))

// raw v_exp_f32 (2^x)
__device__ __forceinline__ float exp2_f(float x) {
  float r; asm("v_exp_f32 %0, %1" : "=v"(r) : "v"(x)); return r;
}
__device__ __forceinline__ float exp2n_g(float u) {
  return exp2_f(fminf(-u, 126.f));
}
__device__ __forceinline__ float sig_u(float u)  { return rcp_f(1.f + exp2n_g(u)); }
__device__ __forceinline__ float tanh_u(float u) {
  float e2 = exp2n_g(u);
  return (1.f - e2) * rcp_f(1.f + e2);
}
__device__ __forceinline__ float tanh_c(float c) {
  return tanh_u(c * 2.8853900817779268f);
}

constexpr float L2E  = 1.4426950408889634f;
constexpr float L2E2 = 2.8853900817779268f;

// f32 -> f16 RNE
__device__ unsigned f16rne(float f) {
  unsigned u = __float_as_uint(f);
  unsigned s = (u >> 16) & 0x8000u;
  int e = (int)((u >> 23) & 0xff) - 127;
  unsigned m = u & 0x7fffffu;
  if (e < -14) return s;
  unsigned h = s | (unsigned)((e + 15) << 10) | (m >> 13);
  unsigned rem = m & 0x1fffu;
  h += (rem > 0x1000u) || (rem == 0x1000u && (h & 1u));
  return h;
}

// ---- prepass: pack weights in MFMA-B layout, exp2-prescaled ----
// Regions (8192 dwords each): A=[0)Whh0(w0)  B=[8192)Whh1(w2)  C=[16384)Wih1(w1/w3)
// Entry: lane l (c=l&15, g=l>>4), dword d: n=d>>3 (N-tile), s=(d>>2)&1 (K-slab),
//   q=d&3. Packs W[n*16+c][s*32+8g+2q .. +1] * scale, scale=2log2e iff n>>2==2.
// Region E [24576,25088): head Wlin as before (unscaled).
__global__ void pack_w(const float* __restrict__ Whh0,
                       const float* __restrict__ Whh1,
                       const float* __restrict__ Wih1,
                       const float* __restrict__ Wlin,
                       unsigned* __restrict__ ws) {
  if (blockIdx.x == 0 && threadIdx.x == 0) ws[FLAG] = 0u;
  int i = blockIdx.x * 256 + threadIdx.x;
  if (i >= 25088) return;
  float v0, v1, sc = 1.f;
  if (i < 24576) {
    int w = i >> 13, rem = i & 8191, l = rem >> 7, d = rem & 127;
    int n = d >> 3, s = (d >> 2) & 1, q = d & 3;
    int c = l & 15, g = l >> 4;
    int row = n * 16 + c;
    int col = s * 32 + 8 * g + 2 * q;
    const float* src = (w == 0) ? Whh0 : (w == 1) ? Whh1 : Wih1;
    v0 = src[row * 64 + col]; v1 = src[row * 64 + col + 1];
    sc = ((n >> 2) == 2) ? L2E2 : L2E;
  } else {
    int j = i - 24576, l = j >> 3, d = j & 7;
    int m = l >> 2, kq = l & 3, k = kq * 16 + 2 * d;
    v0 = Wlin[m * 64 + k]; v1 = Wlin[m * 64 + k + 1];
  }
  ws[i] = f16rne(v0 * sc) | (f16rne(v1 * sc) << 16);
}

#define DECLW32(wp)                                                            \
  u4 W0=(wp)[0],  W1=(wp)[1],  W2=(wp)[2],  W3=(wp)[3],                        \
     W4=(wp)[4],  W5=(wp)[5],  W6=(wp)[6],  W7=(wp)[7],                        \
     W8=(wp)[8],  W9=(wp)[9],  W10=(wp)[10],W11=(wp)[11],                      \
     W12=(wp)[12],W13=(wp)[13],W14=(wp)[14],W15=(wp)[15],                      \
     W16=(wp)[16],W17=(wp)[17],W18=(wp)[18],W19=(wp)[19],                      \
     W20=(wp)[20],W21=(wp)[21],W22=(wp)[22],W23=(wp)[23],                      \
     W24=(wp)[24],W25=(wp)[25],W26=(wp)[26],W27=(wp)[27],                      \
     W28=(wp)[28],W29=(wp)[29],W30=(wp)[30],W31=(wp)[31]

#define PINW8(a,b,c,d,e,f,g,h)                                                 \
  asm volatile("" : "+v"(a), "+v"(b), "+v"(c), "+v"(d),                        \
                    "+v"(e), "+v"(f), "+v"(g), "+v"(h))
#define PINALL() { PINW8(W0,W1,W2,W3,W4,W5,W6,W7);                             \
                   PINW8(W8,W9,W10,W11,W12,W13,W14,W15);                       \
                   PINW8(W16,W17,W18,W19,W20,W21,W22,W23);                     \
                   PINW8(W24,W25,W26,W27,W28,W29,W30,W31); }

// 16-tile MFMA block: A0u/A1u = K-slab fragments (h), W0..W31 = B fragments.
#define MFMA16(A0u, A1u)                                                       \
  f4 a0  = mf(A0u, W0,  Z4); a0  = mf(A1u, W1,  a0);                           \
  f4 a1  = mf(A0u, W2,  Z4); a1  = mf(A1u, W3,  a1);                           \
  f4 a2  = mf(A0u, W4,  Z4); a2  = mf(A1u, W5,  a2);                           \
  f4 a3  = mf(A0u, W6,  Z4); a3  = mf(A1u, W7,  a3);                           \
  f4 a4  = mf(A0u, W8,  Z4); a4  = mf(A1u, W9,  a4);                           \
  f4 a5  = mf(A0u, W10, Z4); a5  = mf(A1u, W11, a5);                           \
  f4 a6  = mf(A0u, W12, Z4); a6  = mf(A1u, W13, a6);                           \
  f4 a7  = mf(A0u, W14, Z4); a7  = mf(A1u, W15, a7);                           \
  f4 a8  = mf(A0u, W16, Z4); a8  = mf(A1u, W17, a8);                           \
  f4 a9  = mf(A0u, W18, Z4); a9  = mf(A1u, W19, a9);                           \
  f4 a10 = mf(A0u, W20, Z4); a10 = mf(A1u, W21, a10);                          \
  f4 a11 = mf(A0u, W22, Z4); a11 = mf(A1u, W23, a11);                          \
  f4 a12 = mf(A0u, W24, Z4); a12 = mf(A1u, W25, a12);                          \
  f4 a13 = mf(A0u, W26, Z4); a13 = mf(A1u, W27, a13);                          \
  f4 a14 = mf(A0u, W28, Z4); a14 = mf(A1u, W29, a14);                          \
  f4 a15 = mf(A0u, W30, Z4); a15 = mf(A1u, W31, a15);

__global__ __launch_bounds__(256)
__attribute__((amdgpu_waves_per_eu(1, 1)))
void rnn_fused(
    const float* __restrict__ y,
    const float* __restrict__ Wih0, const float* __restrict__ bih0,
    const float* __restrict__ bhh0,
    const float* __restrict__ bih1, const float* __restrict__ bhh1,
    const float* __restrict__ blin,
    unsigned* __restrict__ ws,
    float* __restrict__ out)
{
  const int tid = threadIdx.x;
  const int w = tid >> 6;

  if (blockIdx.x != 0) {
    // ====== spinner WGs: dense ILP-8 FMA, poll flag every 2048 FMAs ======
    const int* flag = (const int*)(ws + FLAG);
    float c0 = 1.00f, c1 = 1.01f, c2 = 1.02f, c3 = 1.03f;
    float c4 = 1.04f, c5 = 1.05f, c6 = 1.06f, c7 = 1.07f;
    const float mm = 0.999999f, cc = 1e-6f;
    while (__hip_atomic_load(flag, __ATOMIC_RELAXED, __HIP_MEMORY_SCOPE_AGENT) == 0) {
      #pragma unroll 16
      for (int q = 0; q < 256; ++q) {
        c0 = fmaf(c0, mm, cc); c1 = fmaf(c1, mm, cc);
        c2 = fmaf(c2, mm, cc); c3 = fmaf(c3, mm, cc);
        c4 = fmaf(c4, mm, cc); c5 = fmaf(c5, mm, cc);
        c6 = fmaf(c6, mm, cc); c7 = fmaf(c7, mm, cc);
      }
    }
    asm volatile("" :: "v"(c0), "v"(c1), "v"(c2), "v"(c3),
                       "v"(c4), "v"(c5), "v"(c6), "v"(c7));
    return;
  }

  // rings: block j occupies slots [j*B .. j*B+B) & (RS-1); adjacent blocks in
  // disjoint halves -> cross-wave same-slot reuse >= 1 barrier apart.
  __shared__ __align__(16) unsigned h0r[RS * 32];    // h0 f16 by element, 8 KB
  __shared__ __align__(16) unsigned h1r[RS * 32];    // h1 f16 by element, 8 KB
  __shared__ __align__(16) float    xpf[RS * 320];   // xp f32 [col][tile] s20, 80 KB

  for (int j = tid; j < RS * 32; j += 256) { h0r[j] = 0u; h1r[j] = 0u; }
  __syncthreads();

  const f4 Z4 = {0.f, 0.f, 0.f, 0.f};

  if (w == 0) {
    // ================= wave0: layer-0 recurrence via MFMA =================
    __builtin_amdgcn_s_setprio(1);
    const int e = tid, g = e >> 4;
    const bool b0 = (g & 1) != 0, b1 = (g & 2) != 0;
    const u4* wp = (const u4*)(ws + e * 128);          // Whh0, MFMA-B layout
    DECLW32(wp);
    float bbi = (bih0[e] + bhh0[e]) * L2E;
    float bbf = (bih0[64 + e] + bhh0[64 + e]) * L2E;
    float bbg = (bih0[128 + e] + bhh0[128 + e]) * L2E2;
    float bbo = (bih0[192 + e] + bhh0[192 + e]) * L2E;
    float wii = Wih0[e] * L2E, wif = Wih0[64 + e] * L2E;
    float wig = Wih0[128 + e] * L2E2, wio = Wih0[192 + e] * L2E;
    float c0 = 0.f;
    float ylv = y[e & (B - 1)];
    _Float16* h0h = (_Float16*)h0r;

    for (int k = 0; k < K_SS; ++k) {
      if (k < NB) {
        float yln = (k + 1 < NB) ? y[(k + 1) * B + (e & (B - 1))] : 0.f;
        const int base = k * B;
        #pragma unroll 1
        for (int i = 0; i < B; ++i) {
          const int s = base + i;
          PINALL();
          float ys = __builtin_bit_cast(float,
              __builtin_amdgcn_readlane(__builtin_bit_cast(int, ylv), i));
          const u4* ap = (const u4*)(h0r + ((s - 1) & (RS - 1)) * 32);
          u4 A0u = ap[g], A1u = ap[4 + g];             // h slabs (bcast per group)
          MFMA16(A0u, A1u)
          float ti = sel4(a0[0],  a1[0],  a2[0],  a3[0],  b0, b1);
          float tf = sel4(a4[0],  a5[0],  a6[0],  a7[0],  b0, b1);
          float tg = sel4(a8[0],  a9[0],  a10[0], a11[0], b0, b1);
          float to = sel4(a12[0], a13[0], a14[0], a15[0], b0, b1);
          float I = sig_u(ti + fmaf(ys, wii, bbi));
          float F = sig_u(tf + fmaf(ys, wif, bbf));
          float G = tanh_u(tg + fmaf(ys, wig, bbg));
          float O = sig_u(to + fmaf(ys, wio, bbo));
          c0 = fmaf(F, c0, I * G);
          float h = O * tanh_c(c0);
          h0h[(s & (RS - 1)) * 64 + e] = (_Float16)h;  // ds_write_b16
        }
        ylv = yln;
      }
      BARRIER();
    }
  } else if (w == 1 || w == 3) {
    // == wave1/wave3: xp1 = Wih1*h0+b via MFMA (block k-1, split 16 steps) ==
    //    wave3 additionally owns the head (block k-3, all 32 steps).
    const int e = tid & 63, g = e >> 4, c = e & 15;
    const bool b0 = (g & 1) != 0, b1 = (g & 2) != 0;
    const int ilo = (w == 1) ? 0 : 16;
    const u4* wp = (const u4*)(ws + 16384 + e * 128);  // Wih1, MFMA-B layout
    DECLW32(wp);
    const u4* hwp = (const u4*)(ws + 24576 + e * 8);
    u4 HW0 = hwp[0], HW1 = hwp[1];
    // per-lane biases for the 4 tiles this lane writes (tiles 4g..4g+3, col c)
    float bbx, bby, bbz, bbw;
    {
      int R0 = (4 * g + 0) * 16 + c, R1 = (4 * g + 1) * 16 + c;
      int R2 = (4 * g + 2) * 16 + c, R3 = (4 * g + 3) * 16 + c;
      float s0 = (((4 * g + 0) >> 2) == 2) ? L2E2 : L2E;
      float s1 = (((4 * g + 1) >> 2) == 2) ? L2E2 : L2E;
      float s2 = (((4 * g + 2) >> 2) == 2) ? L2E2 : L2E;
      float s3 = (((4 * g + 3) >> 2) == 2) ? L2E2 : L2E;
      bbx = (bih1[R0] + bhh1[R0]) * s0; bby = (bih1[R1] + bhh1[R1]) * s1;
      bbz = (bih1[R2] + bhh1[R2]) * s2; bbw = (bih1[R3] + bhh1[R3]) * s3;
    }
    const int m = e >> 2, kq = e & 3;
    float bl = (kq == 0) ? blin[m] : 0.f;

    for (int k = 0; k < K_SS; ++k) {
      if (k >= 1 && k <= NB) {                         // xp1 for block k-1
        const int base = (k - 1) * B;
        #pragma unroll 1
        for (int i = ilo; i < ilo + 16; ++i) {
          const int t = base + i;
          const int slot = t & (RS - 1);
          PINALL();
          const u4* ap = (const u4*)(h0r + slot * 32);
          u4 A0u = ap[g], A1u = ap[4 + g];
          MFMA16(A0u, A1u)
          // lane writes tiles 4g+j at [c][4g+j]; tile (4g+j) = sel by g
          float vx = sel4(a0[0], a4[0], a8[0],  a12[0], b0, b1) + bbx;
          float vy = sel4(a1[0], a5[0], a9[0],  a13[0], b0, b1) + bby;
          float vz = sel4(a2[0], a6[0], a10[0], a14[0], b0, b1) + bbz;
          float vw = sel4(a3[0], a7[0], a11[0], a15[0], b0, b1) + bbw;
          f4 v = {vx, vy, vz, vw};
          *(f4*)(xpf + slot * 320 + c * 20 + 4 * g) = v;   // one ds_write_b128
        }
      }
      if (w == 3 && k >= 3) {                          // head for block k-3
        const int base = (k - 3) * B;
        #pragma unroll 1
        for (int i = 0; i < B; ++i) {
          const int t = base + i;
          const int slot = t & (RS - 1);
          const u4* h1p = (const u4*)(h1r + slot * 32 + kq * 8);
          u4 X0 = h1p[0], X1 = h1p[1];
          float r2 = 0.f;
          DP4(r2, HW0, X0) DP4(r2, HW1, X1)
          r2 += DPPX1(r2);
          r2 += DPPX2(r2);                             // sum over kq (quad)
          if (kq == 0) out[t * 16 + m] = r2 + bl;
        }
      }
      BARRIER();
    }
  } else {
    // ============ wave2: layer-1 recurrence via MFMA (block k-2) ============
    __builtin_amdgcn_s_setprio(1);
    const int e = tid - 128, g = e >> 4, c = e & 15;
    const bool b0 = (g & 1) != 0, b1 = (g & 2) != 0;
    const u4* wp = (const u4*)(ws + 8192 + e * 128);   // Whh1, MFMA-B layout
    DECLW32(wp);
    float c1 = 0.f;
    _Float16* h1h = (_Float16*)h1r;

    for (int k = 0; k < K_SS; ++k) {
      if (k >= 2 && k <= NB + 1) {
        const int base = (k - 2) * B;
        #pragma unroll 1
        for (int i = 0; i < B; ++i) {
          const int t = base + i;
          const int slot = t & (RS - 1);
          PINALL();
          const float* xb = xpf + slot * 320 + c * 20;
          float xi = xb[g], xf = xb[4 + g], xg2 = xb[8 + g], xo = xb[12 + g];
          const u4* ap = (const u4*)(h1r + ((t - 1) & (RS - 1)) * 32);
          u4 A0u = ap[g], A1u = ap[4 + g];
          MFMA16(A0u, A1u)
          float ti = sel4(a0[0],  a1[0],  a2[0],  a3[0],  b0, b1);
          float tf = sel4(a4[0],  a5[0],  a6[0],  a7[0],  b0, b1);
          float tg = sel4(a8[0],  a9[0],  a10[0], a11[0], b0, b1);
          float to = sel4(a12[0], a13[0], a14[0], a15[0], b0, b1);
          float I = sig_u(ti + xi);
          float F = sig_u(tf + xf);
          float G = tanh_u(tg + xg2);
          float O = sig_u(to + xo);
          c1 = fmaf(F, c1, I * G);
          float h = O * tanh_c(c1);
          h1h[slot * 64 + e] = (_Float16)h;            // ds_write_b16
        }
      }
      BARRIER();
    }
  }

  // all four waves done: release the spinner WGs
  __syncthreads();
  if (tid == 0)
    __hip_atomic_store((int*)(ws + FLAG), 1, __ATOMIC_RELEASE,
                       __HIP_MEMORY_SCOPE_AGENT);
}

extern "C" void kernel_launch(void* const* d_in, const int* in_sizes, int n_in,
                              void* d_out, int out_size, void* d_ws, size_t ws_size,
                              hipStream_t stream) {
  const float* y    = (const float*)d_in[0];
  const float* Wih0 = (const float*)d_in[1];
  const float* Whh0 = (const float*)d_in[2];
  const float* bih0 = (const float*)d_in[3];
  const float* bhh0 = (const float*)d_in[4];
  const float* Wih1 = (const float*)d_in[5];
  const float* Whh1 = (const float*)d_in[6];
  const float* bih1 = (const float*)d_in[7];
  const float* bhh1 = (const float*)d_in[8];
  const float* Wlin = (const float*)d_in[9];
  const float* blin = (const float*)d_in[10];
  unsigned* ws = (unsigned*)d_ws;                // 25089 dwords ~= 100 KB

  pack_w<<<dim3(98), dim3(256), 0, stream>>>(Whh0, Whh1, Wih1, Wlin, ws);
  rnn_fused<<<dim3(256), dim3(256), 0, stream>>>(
      y, Wih0, bih0, bhh0, bih1, bhh1, blin, ws, (float*)d_out);
}